// Round 1
// baseline (203.693 us; speedup 1.0000x reference)
//
#include <hip/hip_runtime.h>

namespace {

constexpr int T = 200;
constexpr int D = 128;
constexpr int CH0 = 112;   // rows in chunk 0
constexpr int CH1 = 88;    // rows in chunk 1

typedef float f32x4 __attribute__((ext_vector_type(4)));
typedef short bf16x8 __attribute__((ext_vector_type(8)));

__device__ __forceinline__ short f2bf(float f) {
  unsigned u = __float_as_uint(f);
  return (short)((u + 0x7FFFu + ((u >> 16) & 1u)) >> 16);  // RNE
}

__device__ __forceinline__ void async_cp16(const void* g, void* l) {
  void* gnc = (void*)g;
  __builtin_amdgcn_global_load_lds((__attribute__((address_space(1))) void*)gnc,
                                   (__attribute__((address_space(3))) void*)l,
                                   16, 0, 0);
}

// LDS float layout
// [0, 14336)       K chunk: 112 rows x 128 f32, XOR-swizzled (byte ^= (row&7)<<4)
// [14336, 15232)   spart[8][112]   (reused as pout[4][128] in the epilogue)
// [15232, 15488)   u2[2][128]
// [15488, 15600)   wts[112]
// [15600, 15608)   red[8]
constexpr int OFF_SPART = 14336;
constexpr int OFF_U2    = 15232;
constexpr int OFF_WTS   = 15488;
constexpr int OFF_RED   = 15600;
constexpr int SMEM_F    = 15608;

__global__ __launch_bounds__(512, 4) void din_kernel(
    const float* __restrict__ qg, const float* __restrict__ keysg,
    const void* __restrict__ maskg, const float* __restrict__ w1g,
    const float* __restrict__ b1g, const float* __restrict__ pag,
    const float* __restrict__ w2g, const float* __restrict__ b2g,
    float* __restrict__ outg) {
  __shared__ __align__(16) float smem[SMEM_F];
  float* spart = smem + OFF_SPART;
  float* u2    = smem + OFF_U2;
  float* wts   = smem + OFF_WTS;
  float* red   = smem + OFF_RED;

  const int tid  = threadIdx.x;
  const int b    = blockIdx.x;
  const int wid  = tid >> 6;
  const int lane = tid & 63;
  const int lrow = lane >> 4;        // 0..3
  const int lcol = lane & 15;        // 0..15
  const int dw   = wid * 16 + lcol;  // this lane's d column (d-split across 8 waves)

  const float* qb    = qg + (size_t)b * D;
  const float* keysB = keysg + (size_t)b * T * D;

  // ---- mask dtype detector: int32 / uint8 / float32 (wave-uniform, no barrier) ----
  int mcode;
  {
    unsigned v = ((const unsigned*)maskg)[lane];  // first 256 bytes, values are 0/1
    unsigned c0 = v & 255u, c1 = (v >> 8) & 255u, c2 = (v >> 16) & 255u, c3 = v >> 24;
    bool weird = (c0 == 0x80u) | (c0 == 0x3Fu) | (c1 == 0x80u) | (c1 == 0x3Fu) |
                 (c2 == 0x80u) | (c2 == 0x3Fu) | (c3 == 0x80u) | (c3 == 0x3Fu);
    bool nz = (v & 0xFFFFFF00u) != 0u;
    unsigned long long bw = __ballot(weird);
    unsigned long long bn = __ballot(nz);
    mcode = bw ? 2 : (bn ? 1 : 0);  // 2=f32, 1=byte, 0=int32
  }

  const float pa  = pag[0];
  const float b2v = b2g[0];
  const float w2d = w2g[dw];

  // ---- issue chunk-0 staging: keys rows 0..111 -> LDS fp32, source-swizzled ----
  for (int i = wid; i < (CH0 >> 1); i += 8) {
    int row = 2 * i + (lane >> 5);
    int colphys = (lane & 31) * 16;
    int fbyte = colphys ^ ((row & 7) << 4);
    const char* src = (const char*)(keysB + (size_t)row * D) + fbyte;
    async_cp16(src, (char*)smem + i * 1024);
  }

  // ---- per-lane M fragments: M[d][f] = w1[d][128+f] - w1[d][256+f] + w1[d][384+f]*q[f]
  // B-operand layout of mfma_f32_16x16x32_bf16: lane holds B[k=f0+lrow*8+j][n=lcol]
  bf16x8 mfr[4];
  {
    const float* w1row = w1g + (size_t)dw * 512;
    for (int ks = 0; ks < 4; ++ks) {
      int f0 = ks * 32 + lrow * 8;
      f32x4 q0  = *(const f32x4*)(qb + f0);
      f32x4 q1  = *(const f32x4*)(qb + f0 + 4);
      f32x4 bB0 = *(const f32x4*)(w1row + 128 + f0);
      f32x4 bB1 = *(const f32x4*)(w1row + 128 + f0 + 4);
      f32x4 cC0 = *(const f32x4*)(w1row + 256 + f0);
      f32x4 cC1 = *(const f32x4*)(w1row + 256 + f0 + 4);
      f32x4 dD0 = *(const f32x4*)(w1row + 384 + f0);
      f32x4 dD1 = *(const f32x4*)(w1row + 384 + f0 + 4);
      bf16x8 m;
      m[0] = f2bf(bB0.x - cC0.x + dD0.x * q0.x);
      m[1] = f2bf(bB0.y - cC0.y + dD0.y * q0.y);
      m[2] = f2bf(bB0.z - cC0.z + dD0.z * q0.z);
      m[3] = f2bf(bB0.w - cC0.w + dD0.w * q0.w);
      m[4] = f2bf(bB1.x - cC1.x + dD1.x * q1.x);
      m[5] = f2bf(bB1.y - cC1.y + dD1.y * q1.y);
      m[6] = f2bf(bB1.z - cC1.z + dD1.z * q1.z);
      m[7] = f2bf(bB1.w - cC1.w + dD1.w * q1.w);
      mfr[ks] = m;
    }
  }

  // ---- u[d] = sum_f q[f]*(w1[d][f] + w1[d][256+f]) + b1[d], split over 2 f-halves
  if (tid < 256) {
    int d = tid & 127, fh = tid >> 7;
    const float* arow = w1g + (size_t)d * 512 + fh * 64;
    const float* crow = arow + 256;
    const float* qh   = qb + fh * 64;
    float acc = 0.f;
    #pragma unroll
    for (int i = 0; i < 16; ++i) {
      f32x4 qv = *(const f32x4*)(qh + i * 4);
      f32x4 av = *(const f32x4*)(arow + i * 4);
      f32x4 cv = *(const f32x4*)(crow + i * 4);
      acc += qv.x * (av.x + cv.x) + qv.y * (av.y + cv.y) +
             qv.z * (av.z + cv.z) + qv.w * (av.w + cv.w);
    }
    if (fh == 0) acc += b1g[d];
    u2[fh * 128 + d] = acc;
  }

  __syncthreads();  // chunk-0 staged (barrier drains vmcnt), u2 ready

  const float u_d = u2[dw] + u2[128 + dw];

  float m_run = -1e9f, denom_run = 0.f, accPV = 0.f;
  const int dpv = tid & 127, q4 = tid >> 7;

  for (int c = 0; c < 2; ++c) {
    const int tbase = c * CH0;
    const int nt = c ? 6 : 7;

    // ---- scores: H = K*M^T via MFMA; +u, PReLU, dot w2; partial over wave's 16 d
    for (int tt = 0; tt < nt; ++tt) {
      f32x4 acc = {0.f, 0.f, 0.f, 0.f};
      int row = tt * 16 + lcol;          // A row = lane&15
      int swz = (row & 7) << 4;
      const char* base = (const char*)smem + (size_t)row * 512;
      #pragma unroll
      for (int ks = 0; ks < 4; ++ks) {
        int fb = (ks * 32 + lrow * 8) * 4;
        f32x4 a0 = *(const f32x4*)(base + (fb ^ swz));
        f32x4 a1 = *(const f32x4*)(base + ((fb + 16) ^ swz));
        bf16x8 af;
        af[0] = f2bf(a0.x); af[1] = f2bf(a0.y); af[2] = f2bf(a0.z); af[3] = f2bf(a0.w);
        af[4] = f2bf(a1.x); af[5] = f2bf(a1.y); af[6] = f2bf(a1.z); af[7] = f2bf(a1.w);
        acc = __builtin_amdgcn_mfma_f32_16x16x32_bf16(af, mfr[ks], acc, 0, 0, 0);
      }
      #pragma unroll
      for (int j = 0; j < 4; ++j) {      // C/D row = (lane>>4)*4 + j, col = lane&15
        float h = acc[j] + u_d;
        h = (h >= 0.f) ? h : pa * h;     // PReLU
        float pj = h * w2d;
        pj += __shfl_xor(pj, 1);
        pj += __shfl_xor(pj, 2);
        pj += __shfl_xor(pj, 4);
        pj += __shfl_xor(pj, 8);         // sum over this wave's 16 d
        if (lcol == 0) spart[wid * 112 + tt * 16 + lrow * 4 + j] = pj;
      }
    }
    __syncthreads();  // spart ready

    // ---- chunk softmax (online) ----
    float s = -1e9f;
    bool valid = false;
    if (tid < 128) {
      if (tid < 112) {
        float ssum = b2v;
        #pragma unroll
        for (int w = 0; w < 8; ++w) ssum += spart[w * 112 + tid];
        int t = tbase + tid;
        if (t < T) {
          bool mk;
          if (mcode == 0)      mk = ((const int*)maskg)[(size_t)b * T + t] != 0;
          else if (mcode == 1) mk = ((const unsigned char*)maskg)[(size_t)b * T + t] != 0;
          else                 mk = ((const float*)maskg)[(size_t)b * T + t] != 0.f;
          valid = mk;
        }
        if (valid) s = ssum;
      }
      float mm = s;
      #pragma unroll
      for (int off = 1; off < 64; off <<= 1) mm = fmaxf(mm, __shfl_xor(mm, off));
      if (lane == 0) red[wid] = mm;
    }
    __syncthreads();  // chunk max ready
    float m_new = fmaxf(m_run, fmaxf(red[0], red[1]));
    float scale = expf(m_run - m_new);
    if (tid < 128) {
      float pval = valid ? expf(s - m_new) : 0.f;
      if (tid < 112) wts[tid] = pval;
      float ps = pval;
      #pragma unroll
      for (int off = 1; off < 64; off <<= 1) ps += __shfl_xor(ps, off);
      if (lane == 0) red[4 + wid] = ps;
    }
    __syncthreads();  // wts + chunk sums ready
    denom_run = denom_run * scale + red[4] + red[5];
    m_run = m_new;

    // ---- PV accumulate from LDS fp32 (swizzled reads, conflict-free) ----
    accPV *= scale;
    #pragma unroll 4
    for (int i = 0; i < 28; ++i) {
      int trel = q4 * 28 + i;
      float wt = wts[trel];               // wave-uniform -> uniform branch
      if (wt != 0.f) {
        const char* p = (const char*)smem + (size_t)trel * 512 +
                        ((4 * dpv) ^ ((trel & 7) << 4));
        accPV += wt * (*(const float*)p);
      }
    }
    __syncthreads();  // everyone done reading K chunk + wts

    if (c == 0) {  // stage chunk 1: keys rows 112..199 over rows 0..87
      for (int i = wid; i < (CH1 >> 1); i += 8) {
        int row = 2 * i + (lane >> 5);
        int colphys = (lane & 31) * 16;
        int fbyte = colphys ^ ((row & 7) << 4);
        const char* src = (const char*)(keysB + (size_t)(CH0 + row) * D) + fbyte;
        async_cp16(src, (char*)smem + i * 1024);
      }
      __syncthreads();  // chunk-1 staged
    }
  }

  // ---- combine PV partials, normalize, write ----
  spart[q4 * 128 + dpv] = accPV;  // reuse spart as pout[4][128]
  __syncthreads();
  if (tid < 128) {
    float o = spart[tid] + spart[128 + tid] + spart[256 + tid] + spart[384 + tid];
    float inv = (denom_run > 0.f) ? 1.0f / denom_run : 0.f;
    outg[(size_t)b * D + tid] = o * inv;
  }
}

}  // namespace

extern "C" void kernel_launch(void* const* d_in, const int* in_sizes, int n_in,
                              void* d_out, int out_size, void* d_ws, size_t ws_size,
                              hipStream_t stream) {
  (void)in_sizes; (void)n_in; (void)out_size; (void)d_ws; (void)ws_size;
  const float* q    = (const float*)d_in[0];
  const float* keys = (const float*)d_in[1];
  const void*  mask = d_in[2];
  const float* w1   = (const float*)d_in[3];
  const float* b1   = (const float*)d_in[4];
  const float* pa   = (const float*)d_in[5];
  const float* w2   = (const float*)d_in[6];
  const float* b2   = (const float*)d_in[7];
  float* out = (float*)d_out;
  din_kernel<<<2048, 512, 0, stream>>>(q, keys, mask, w1, b1, pa, w2, b2, out);
}